// Round 9
// baseline (1755.433 us; speedup 1.0000x reference)
//
#include <hip/hip_runtime.h>
#include <cstdint>
#include <cstddef>
#include <climits>

// DacResidualVectorQuantize on MI355X. Exact-class (f64-internal, f32
// materialization) chain + cluster-argmin (lowest index within ~2 f32 ulp of
// exact min) — R7 green, R8 1731us. R9: k_upd/k_fold occupancy 25%->100%
// (NCH 8->32 => 8192 waves) + 2-deep load prefetch; runtime-adaptive NCH.

#define NCOL 32768
#define QBASE 33554432ull  // 16*1024*2048 (quant region == residual storage)
#define PREF32 2e-5f       // f32 prefilter band (score units)
#define TOLS 1.25e-7       // score tolerance (= dist tol 2.5e-7 / 2)
#define CAP 6
#define DCHMAX 128

// f32 round of exact sum of 8 f32 values
__device__ __forceinline__ float s8_exact(const float* x) {
  double a = 0.0;
#pragma unroll
  for (int k = 0; k < 8; ++k) a += (double)x[k];
  return (float)a;
}

// -------------------------------------------------------------- K1: prep
__global__ __launch_bounds__(256) void k_prep(
    const float* __restrict__ in_v, const float* __restrict__ in_g,
    const float* __restrict__ out_v, const float* __restrict__ out_g,
    const float* __restrict__ cbk, float* __restrict__ w_inT,
    float* __restrict__ w_outT, float* __restrict__ cnf,
    float* __restrict__ cn2, double* __restrict__ loss_acc) {
#pragma clang fp contract(off)
  int id = blockIdx.x * 256 + threadIdx.x;
  if (id == 0) loss_acc[0] = 0.0;
  if (id < 72) {
    int i = id >> 3, o = id & 7;
    const float* v = in_v + (size_t)id * 1024;
    double n2 = 0.0;
    for (int d = 0; d < 1024; ++d) {
      float sqv = v[d] * v[d];
      n2 += (double)sqv;
    }
    float n2f = (float)n2;
    float nrm = (float)sqrt((double)n2f);
    float g = in_g[id];
    for (int d = 0; d < 1024; ++d) {
      float gv = g * v[d];
      float w = gv / nrm;
      w_inT[((size_t)i * 1024 + d) * 8 + o] = w;
    }
  } else if (id < 72 + 9216) {
    int r = id - 72;  // (i,d) row of out_v [9][1024][8]
    const float* v = out_v + (size_t)r * 8;
    float sq[8];
#pragma unroll
    for (int k = 0; k < 8; ++k) sq[k] = v[k] * v[k];
    float n2f = s8_exact(sq);
    float nrm = (float)sqrt((double)n2f);
    float g = out_g[r];
#pragma unroll
    for (int k = 0; k < 8; ++k) {
      float gv = g * v[k];
      w_outT[(size_t)r * 8 + k] = gv / nrm;
    }
  } else if (id < 72 + 9216 + 9216) {
    int r = id - 72 - 9216;  // code row (i*1024+c)
    const float* v = cbk + (size_t)r * 8;
    float sq[8];
#pragma unroll
    for (int k = 0; k < 8; ++k) sq[k] = v[k] * v[k];
    float n2f = s8_exact(sq);
    float nrm = (float)sqrt((double)n2f);
    float den = fmaxf(nrm, 1e-12f);
    float cn[8], c2[8];
#pragma unroll
    for (int k = 0; k < 8; ++k) {
      cn[k] = v[k] / den;
      cnf[(size_t)r * 8 + k] = cn[k];
      c2[k] = cn[k] * cn[k];
    }
    cn2[r] = s8_exact(c2);
  }
}

// ---------------- K2: initial z_e fold partials from h (stage 0 weights)
// grid (64, nch) x 256 thr; thread = 2 cols (float2), dch d-rows; prefetch.
__global__ __launch_bounds__(256) void k_fold(
    const float* __restrict__ h, const float* __restrict__ w_inT,
    double* __restrict__ part, int nch, int dch) {
#pragma clang fp contract(off)
  __shared__ float wl[DCHMAX][8];
  int tid = threadIdx.x;
  int dq = blockIdx.y, d0 = dq * dch;
  const float* w = w_inT + (size_t)d0 * 8;
  for (int u = tid; u < dch * 8; u += 256) wl[u >> 3][u & 7] = w[u];
  __syncthreads();

  int col0 = blockIdx.x * 512 + tid * 2;
  int b = col0 >> 11, t = col0 & 2047;
  size_t base = (size_t)b * 1024 * 2048 + (size_t)d0 * 2048 + t;
  double za0[8] = {0, 0, 0, 0, 0, 0, 0, 0};
  double za1[8] = {0, 0, 0, 0, 0, 0, 0, 0};
  float2 rv = *(const float2*)&h[base];
  for (int dd = 0; dd < dch; ++dd) {
    float2 rnx;
    if (dd + 1 < dch) rnx = *(const float2*)&h[base + (size_t)(dd + 1) * 2048];
    double r0 = (double)rv.x, r1 = (double)rv.y;
#pragma unroll
    for (int o = 0; o < 8; ++o) {
      double wv = (double)wl[dd][o];
      za0[o] = fma(wv, r0, za0[o]);
      za1[o] = fma(wv, r1, za1[o]);
    }
    rv = rnx;
  }
#pragma unroll
  for (int o = 0; o < 8; ++o) {
    double2 pv = {za0[o], za1[o]};
    *(double2*)&part[((size_t)(o * nch + dq)) * NCOL + col0] = pv;
  }
}

// ---------------- K2b: reduce nch partials (ascending order) -> zebuf f32
__global__ __launch_bounds__(256) void k_zred(
    const double* __restrict__ part, float* __restrict__ zebuf, int nch) {
  int id = blockIdx.x * 256 + threadIdx.x;  // [0, 8*NCOL)
  int o = id >> 15;
  int col = id & (NCOL - 1);
  double s = 0.0;
  for (int q = 0; q < nch; ++q)
    s += part[((size_t)(o * nch + q)) * NCOL + col];
  zebuf[(size_t)o * NCOL + col] = (float)s;
}

// -------- K3: select with cluster-argmin (f32 prefilter + f64 rescore)
__global__ __launch_bounds__(256) void k_sel(
    const float* __restrict__ zebuf, const float* __restrict__ in_b,
    const float* __restrict__ cnf, const float* __restrict__ cn2,
    const float* __restrict__ cbk, int i, int nq, float* __restrict__ out,
    float* __restrict__ zqst, double* __restrict__ loss_acc) {
#pragma clang fp contract(off)
  __shared__ float m32[4][64];
  __shared__ double m64[4][64];
  __shared__ int mix[4][64];
  int tid = threadIdx.x;
  int lane = tid & 63;
  int chunk = tid >> 6;
  int col = blockIdx.x * 64 + lane;
  int b = col >> 11, t = col & 2047;

  float z[8];
#pragma unroll
  for (int o = 0; o < 8; ++o)
    z[o] = zebuf[(size_t)o * NCOL + col] + in_b[i * 8 + o];  // add eqn f32

  float sq[8];
#pragma unroll
  for (int k = 0; k < 8; ++k) sq[k] = z[k] * z[k];
  float n2f = s8_exact(sq);
  float nrm = (float)sqrt((double)n2f);
  float den = fmaxf(nrm, 1e-12f);
  float en[8];
#pragma unroll
  for (int k = 0; k < 8; ++k) en[k] = z[k] / den;  // div eqn f32

  const float* cb = cnf + ((size_t)i * 1024 + chunk * 256) * 8;
  const float* c2 = cn2 + (size_t)i * 1024 + chunk * 256;

  // ---- PASS 1: f32 prefilter scan (order-free, FMA ok)
  float b32 = -__builtin_inff();
  for (int c = 0; c < 256; ++c) {
    const float* cp = cb + (size_t)c * 8;
    float s = fmaf(en[0], cp[0], -0.5f * c2[c]);
#pragma unroll
    for (int k = 1; k < 8; ++k) s = fmaf(en[k], cp[k], s);
    b32 = fmaxf(b32, s);
  }
  m32[chunk][lane] = b32;
  __syncthreads();
  float g32 = m32[0][lane];
#pragma unroll
  for (int ch = 1; ch < 4; ++ch) g32 = fmaxf(g32, m32[ch][lane]);
  float cut32 = g32 - PREF32;

  // ---- PASS 2: rescan; f64-rescore prequalified codes, cache them
  double cs[CAP];
  int ci[CAP];
  int cnt = 0;
  double b64 = -1e300;
  for (int c = 0; c < 256; ++c) {
    const float* cp = cb + (size_t)c * 8;
    float s = fmaf(en[0], cp[0], -0.5f * c2[c]);
#pragma unroll
    for (int k = 1; k < 8; ++k) s = fmaf(en[k], cp[k], s);
    if (s >= cut32) {
      double a = 0.0, q = 0.0;
#pragma unroll
      for (int k = 0; k < 8; ++k) {
        double cd = (double)cp[k];
        a = fma((double)en[k], cd, a);
        q = fma(cd, cd, q);
      }
      double s64 = a - 0.5 * q;
      if (s64 > b64) b64 = s64;
      if (cnt < CAP) {
        cs[cnt] = s64;
        ci[cnt] = chunk * 256 + c;
        ++cnt;
      } else {
        int wm = 0;
        double wv = cs[0];
#pragma unroll
        for (int u = 1; u < CAP; ++u)
          if (cs[u] < wv) { wv = cs[u]; wm = u; }
        if (s64 > wv) { cs[wm] = s64; ci[wm] = chunk * 256 + c; }
      }
    }
  }
  m64[chunk][lane] = b64;
  __syncthreads();
  double g64 = m64[0][lane];
#pragma unroll
  for (int ch = 1; ch < 4; ++ch) g64 = fmax(g64, m64[ch][lane]);
  double cut64 = g64 - TOLS;

  int loc = INT_MAX;
  for (int u = 0; u < cnt; ++u)
    if (cs[u] >= cut64 && ci[u] < loc) loc = ci[u];
  mix[chunk][lane] = loc;
  __syncthreads();

  if (chunk == 0) {
    int g = mix[0][lane];
#pragma unroll
    for (int ch = 1; ch < 4; ++ch) g = min(g, mix[ch][lane]);
    size_t idx_base = QBASE;
    size_t lat_base = idx_base + (size_t)16 * nq * 2048;
    out[idx_base + ((size_t)b * nq + i) * 2048 + t] = (float)g;
#pragma unroll
    for (int o = 0; o < 8; ++o)
      out[lat_base + ((size_t)b * (nq * 8) + (i * 8 + o)) * 2048 + t] = z[o];
    const float* zp = &cbk[((size_t)i * 1024 + g) * 8];
    double lsum = 0.0;
#pragma unroll
    for (int k = 0; k < 8; ++k) {
      float zq = zp[k];
      float dlt = zq - z[k];
      float st = z[k] + dlt;  // straight-through, two roundings
      zqst[(size_t)k * NCOL + col] = st;
      float df = z[k] - zq;
      lsum += (double)df * (double)df;
    }
#pragma unroll
    for (int off = 1; off < 64; off <<= 1) lsum += __shfl_xor(lsum, off, 64);
    if (lane == 0) atomicAdd(loss_acc, lsum);
  }
}

// ------- K4: parallel update: q = f32(f64 dot8) + b; residual f32;
//          f64 z_e partials for next stage. grid (64, nch) x 256 thr.
//          2-deep load prefetch. Last stage writes quant = h - resid_new.
__global__ __launch_bounds__(256) void k_upd(
    const float* __restrict__ h, const float* __restrict__ w_outT,
    const float* __restrict__ out_b, const float* __restrict__ w_inT,
    const float* __restrict__ zqst, int i, int nq, float* __restrict__ resid,
    double* __restrict__ part, int nch, int dch) {
#pragma clang fp contract(off)
  __shared__ float wol[DCHMAX][8];
  __shared__ float bol[DCHMAX];
  __shared__ float wnl[DCHMAX][8];
  int tid = threadIdx.x;
  int dq = blockIdx.y, d0 = dq * dch;
  bool last = (i == nq - 1);
  bool first = (i == 0);
  const float* wo = w_outT + ((size_t)i * 1024 + d0) * 8;
  const float* bo = out_b + (size_t)i * 1024 + d0;
  const float* wn = w_inT + ((size_t)(last ? i : i + 1) * 1024 + d0) * 8;
  for (int u = tid; u < dch * 8; u += 256) {
    wol[u >> 3][u & 7] = wo[u];
    wnl[u >> 3][u & 7] = last ? 0.f : wn[u];
  }
  for (int u = tid; u < dch; u += 256) bol[u] = bo[u];
  __syncthreads();

  int col0 = blockIdx.x * 512 + tid * 2;
  int b = col0 >> 11, t = col0 & 2047;
  float s0[8], s1[8];
#pragma unroll
  for (int k = 0; k < 8; ++k) {
    float2 sv = *(const float2*)&zqst[(size_t)k * NCOL + col0];
    s0[k] = sv.x;
    s1[k] = sv.y;
  }
  double za0[8] = {0, 0, 0, 0, 0, 0, 0, 0};
  double za1[8] = {0, 0, 0, 0, 0, 0, 0, 0};
  size_t base = (size_t)b * 1024 * 2048 + (size_t)d0 * 2048 + t;
  const float* src = first ? h : resid;

  float2 rv = *(const float2*)&src[base];
  for (int dd = 0; dd < dch; ++dd) {
    float2 rnx;
    if (dd + 1 < dch)
      rnx = *(const float2*)&src[base + (size_t)(dd + 1) * 2048];
    double a0 = 0.0, a1 = 0.0;
#pragma unroll
    for (int k = 0; k < 8; ++k) {
      double wv = (double)wol[dd][k];
      a0 = fma(wv, (double)s0[k], a0);
      a1 = fma(wv, (double)s1[k], a1);
    }
    float qe0 = (float)a0, qe1 = (float)a1;  // dot_general -> f32 cast
    float bias = bol[dd];
    float q0 = qe0 + bias, q1 = qe1 + bias;  // add eqn f32
    size_t adr = base + (size_t)dd * 2048;
    float rn0 = rv.x - q0, rn1 = rv.y - q1;  // sub eqn f32
    if (last) {
      float2 hv = *(const float2*)&h[adr];
      float2 qq = {hv.x - rn0, hv.y - rn1};  // quant = h - residual_final
      *(float2*)&resid[adr] = qq;
    } else {
      float2 rr = {rn0, rn1};
      *(float2*)&resid[adr] = rr;
      double r0 = (double)rn0, r1 = (double)rn1;
#pragma unroll
      for (int o = 0; o < 8; ++o) {
        double wv = (double)wnl[dd][o];
        za0[o] = fma(wv, r0, za0[o]);
        za1[o] = fma(wv, r1, za1[o]);
      }
    }
    rv = rnx;
  }
  if (!last) {
#pragma unroll
    for (int o = 0; o < 8; ++o) {
      double2 pv = {za0[o], za1[o]};
      *(double2*)&part[((size_t)(o * nch + dq)) * NCOL + col0] = pv;
    }
  }
}

// --------------------------------------------------------- K5: losses
__global__ void k_fin(const double* __restrict__ loss_acc, int nq,
                      float* __restrict__ out) {
  if (threadIdx.x == 0 && blockIdx.x == 0) {
    float v = (float)(loss_acc[0] / 262144.0);  // B*CD*T
    size_t base = QBASE + (size_t)16 * nq * 2048 + (size_t)16 * nq * 8 * 2048;
    out[base] = v;
    out[base + 1] = v;
  }
}

// ------------------------------------------------------------------ launch
extern "C" void kernel_launch(void* const* d_in, const int* in_sizes, int n_in,
                              void* d_out, int out_size, void* d_ws,
                              size_t ws_size, hipStream_t stream) {
  (void)in_sizes; (void)n_in;
  const float* h     = (const float*)d_in[0];
  const float* in_v  = (const float*)d_in[1];
  const float* in_g  = (const float*)d_in[2];
  const float* in_b  = (const float*)d_in[3];
  const float* out_v = (const float*)d_in[4];
  const float* out_g = (const float*)d_in[5];
  const float* out_b = (const float*)d_in[6];
  const float* cbk   = (const float*)d_in[7];
  float* out = (float*)d_out;
  char* ws = (char*)d_ws;

  long long nq_ll = ((long long)out_size - (long long)QBASE - 2) / 294912LL;
  int nq = (int)nq_ll;
  if (nq < 1) nq = 1;
  if (nq > 9) nq = 9;

  size_t off = 0;
  auto alloc = [&](size_t bytes) {
    size_t o = off;
    off += (bytes + 255) & ~(size_t)255;
    return o;
  };
  float*  w_inT  = (float*)(ws + alloc((size_t)9 * 1024 * 8 * 4));
  float*  w_outT = (float*)(ws + alloc((size_t)9 * 1024 * 8 * 4));
  float*  cnf    = (float*)(ws + alloc((size_t)9 * 1024 * 8 * 4));
  float*  cn2    = (float*)(ws + alloc((size_t)9 * 1024 * 4));
  float*  zebuf  = (float*)(ws + alloc((size_t)8 * NCOL * 4));
  float*  zqst   = (float*)(ws + alloc((size_t)8 * NCOL * 4));
  double* lossa  = (double*)(ws + alloc(256));

  // adaptive NCH: prefer 32 (8192 waves, 100% occupancy cap), shrink if ws
  int nch = 32;
  while (nch > 8 && off + (size_t)8 * nch * NCOL * 8 > ws_size) nch >>= 1;
  int dch = 1024 / nch;
  double* part = (double*)(ws + alloc((size_t)8 * nch * NCOL * 8));

  float* resid = out;  // quant region doubles as residual storage

  k_prep<<<dim3(73), 256, 0, stream>>>(in_v, in_g, out_v, out_g, cbk, w_inT,
                                       w_outT, cnf, cn2, lossa);
  k_fold<<<dim3(64, nch), 256, 0, stream>>>(h, w_inT, part, nch, dch);
  k_zred<<<dim3(1024), 256, 0, stream>>>(part, zebuf, nch);
  for (int i = 0; i < nq; ++i) {
    k_sel<<<dim3(512), 256, 0, stream>>>(zebuf, in_b, cnf, cn2, cbk, i, nq,
                                         out, zqst, lossa);
    k_upd<<<dim3(64, nch), 256, 0, stream>>>(h, w_outT, out_b, w_inT, zqst,
                                             i, nq, resid, part, nch, dch);
    if (i < nq - 1) k_zred<<<dim3(1024), 256, 0, stream>>>(part, zebuf, nch);
  }
  k_fin<<<1, 64, 0, stream>>>(lossa, nq, out);
}

// Round 10
// 1170.070 us; speedup vs baseline: 1.5003x; 1.5003x over previous
//
#include <hip/hip_runtime.h>
#include <cstdint>
#include <cstddef>
#include <climits>

// DacResidualVectorQuantize on MI355X. Exact-class (f64-internal, f32
// materialization) chain + cluster-argmin — R7 green (all indices exact).
// R10: FULLY FUSED stage loop — residual lives in registers (16 lanes/column
// x 64 f32), per-stage weights/codebook staged in LDS (stride-10 padding,
// conflict-free b64 reads), single-pass scan with per-lane top-4 cache.
// HBM: read h twice + write outputs (~400MB total vs ~3.5GB before).

#define NCOL 32768
#define QBASE 33554432ull  // 16*1024*2048
#define PREF32 2e-5f       // f32 prefilter band (score units)
#define TOLS 1.25e-7       // score tolerance (= dist tol 2.5e-7 / 2)
#define NEGINF (-__builtin_inff())

// f32 round of exact sum of 8 f32 values
__device__ __forceinline__ float s8_exact(const float* x) {
  double a = 0.0;
#pragma unroll
  for (int k = 0; k < 8; ++k) a += (double)x[k];
  return (float)a;
}

// -------------------------------------------------------------- K1: prep
// blocks [0,72): one block per w_in row (parallel norm reduce).
// blocks [72,144): flat threads for w_out rows (9216) + codebook rows (9216).
__global__ __launch_bounds__(256) void k_prep(
    const float* __restrict__ in_v, const float* __restrict__ in_g,
    const float* __restrict__ out_v, const float* __restrict__ out_g,
    const float* __restrict__ cbk, float* __restrict__ w_inT,
    float* __restrict__ w_outT, float* __restrict__ cnf,
    float* __restrict__ cn2, double* __restrict__ loss_acc) {
#pragma clang fp contract(off)
  __shared__ double red[256];
  int bid = blockIdx.x, tid = threadIdx.x;
  if (bid == 0 && tid == 0) loss_acc[0] = 0.0;
  if (bid < 72) {
    int i = bid >> 3, o = bid & 7;
    const float* v = in_v + (size_t)bid * 1024;
    double p = 0.0;
    for (int d = tid; d < 1024; d += 256) {
      float sqv = v[d] * v[d];  // integer_pow eqn f32
      p += (double)sqv;         // exact accumulation (f64, assoc-free class)
    }
    red[tid] = p;
    __syncthreads();
    for (int s = 128; s > 0; s >>= 1) {
      if (tid < s) red[tid] += red[tid + s];
      __syncthreads();
    }
    float n2f = (float)red[0];             // reduce_sum -> f32 aval
    float nrm = (float)sqrt((double)n2f);  // correctly-rounded f32 sqrt
    float g = in_g[bid];
    for (int d = tid; d < 1024; d += 256) {
      float gv = g * v[d];  // mul eqn f32
      float w = gv / nrm;   // div eqn f32
      w_inT[((size_t)i * 1024 + d) * 8 + o] = w;
    }
  } else {
    int id = (bid - 72) * 256 + tid;
    if (id < 9216) {
      int r = id;  // (i,d) row of out_v [9][1024][8]
      const float* v = out_v + (size_t)r * 8;
      float sq[8];
#pragma unroll
      for (int k = 0; k < 8; ++k) sq[k] = v[k] * v[k];
      float n2f = s8_exact(sq);
      float nrm = (float)sqrt((double)n2f);
      float g = out_g[r];
#pragma unroll
      for (int k = 0; k < 8; ++k) {
        float gv = g * v[k];
        w_outT[(size_t)r * 8 + k] = gv / nrm;
      }
    } else if (id < 18432) {
      int r = id - 9216;  // code row (i*1024+c)
      const float* v = cbk + (size_t)r * 8;
      float sq[8];
#pragma unroll
      for (int k = 0; k < 8; ++k) sq[k] = v[k] * v[k];
      float n2f = s8_exact(sq);
      float nrm = (float)sqrt((double)n2f);
      float den = fmaxf(nrm, 1e-12f);
      float cn[8], c2[8];
#pragma unroll
      for (int k = 0; k < 8; ++k) {
        cn[k] = v[k] / den;
        cnf[(size_t)r * 8 + k] = cn[k];
        c2[k] = cn[k] * cn[k];
      }
      cn2[r] = s8_exact(c2);
    }
  }
}

// ------------------------------------------------ K2: fused 9-stage VQ
// 512 thr = 32 columns x 16 lanes. rr[64] f32 registers = resid slice
// (d = l + 16*j). Per stage: f64 fold -> butterfly -> z; LDS-staged
// weights/codes; single-pass scan + cluster-argmin; in-register update.
__global__ __launch_bounds__(512, 2) void k_fused(
    const float* __restrict__ h, const float* __restrict__ w_inT,
    const float* __restrict__ w_outT, const float* __restrict__ in_b,
    const float* __restrict__ out_b, const float* __restrict__ cnf,
    const float* __restrict__ cn2, const float* __restrict__ cbk, int nq,
    float* __restrict__ out, double* __restrict__ loss_acc) {
#pragma clang fp contract(off)
  __shared__ float wol[10240];   // w_out[i] rows padded to 10
  __shared__ float wnl[10240];   // w_in[i] (fold), then w_in[i+1]
  __shared__ float cnl[10240];   // cn[i] rows padded to 10
  __shared__ float bol[1024];
  __shared__ float c2l[1024];
  __shared__ float hst[64][36];  // h / resid staging tile
  __shared__ double lred[32];

  int tid = threadIdx.x;
  int g = tid >> 4;      // column group 0..31
  int l = tid & 15;      // lane in group
  int b = blockIdx.x >> 6;
  int t0 = (blockIdx.x & 63) * 32;
  int t = t0 + g;

  // preload wnl = w_in[0]
  for (int u = tid; u < 8192; u += 512)
    wnl[(u >> 3) * 10 + (u & 7)] = w_inT[u];

  // ---- load resid = h into registers (coalesced via LDS)
  float rr[64];
#pragma unroll
  for (int cc = 0; cc < 16; ++cc) {
    __syncthreads();
    int row = tid >> 3, c4 = (tid & 7) * 4;
    *(float4*)&hst[row][c4] =
        *(const float4*)&h[((size_t)b * 1024 + cc * 64 + row) * 2048 + t0 + c4];
    __syncthreads();
#pragma unroll
    for (int jj = 0; jj < 4; ++jj) rr[cc * 4 + jj] = hst[l + 16 * jj][g];
  }
  __syncthreads();

  double lsum = 0.0;
  size_t idx_base = QBASE;
  size_t lat_base = QBASE + (size_t)16 * nq * 2048;

  for (int i = 0; i < nq; ++i) {
    // ---- fold: z_e = w_in[i] . resid (f64 exact-class)
    double za[8] = {0, 0, 0, 0, 0, 0, 0, 0};
#pragma unroll
    for (int j = 0; j < 64; ++j) {
      int d = l + 16 * j;
      const float2* wp = (const float2*)&wnl[d * 10];
      float2 wa = wp[0], wb = wp[1], wc = wp[2], wd = wp[3];
      double rv = (double)rr[j];
      za[0] = fma((double)wa.x, rv, za[0]);
      za[1] = fma((double)wa.y, rv, za[1]);
      za[2] = fma((double)wb.x, rv, za[2]);
      za[3] = fma((double)wb.y, rv, za[3]);
      za[4] = fma((double)wc.x, rv, za[4]);
      za[5] = fma((double)wc.y, rv, za[5]);
      za[6] = fma((double)wd.x, rv, za[6]);
      za[7] = fma((double)wd.y, rv, za[7]);
    }
#pragma unroll
    for (int o = 0; o < 8; ++o) {
#pragma unroll
      for (int m = 1; m < 16; m <<= 1) za[o] += __shfl_xor(za[o], m, 64);
    }
    float z[8];
#pragma unroll
    for (int o = 0; o < 8; ++o)
      z[o] = (float)za[o] + in_b[i * 8 + o];  // add eqn f32
    __syncthreads();  // done reading wnl(i) / cnl(i-1)

    // ---- stage loads: w_out[i], bias, cn[i], cn2[i], w_in[i+1]
    {
      const float* so = w_outT + (size_t)i * 8192;
      const float* sc = cnf + (size_t)i * 8192;
      for (int u = tid; u < 8192; u += 512) {
        int du = (u >> 3) * 10 + (u & 7);
        wol[du] = so[u];
        cnl[du] = sc[u];
      }
      const float* sb = out_b + (size_t)i * 1024;
      const float* s2 = cn2 + (size_t)i * 1024;
      for (int u = tid; u < 1024; u += 512) {
        bol[u] = sb[u];
        c2l[u] = s2[u];
      }
      if (i + 1 < nq) {
        const float* sn = w_inT + (size_t)(i + 1) * 8192;
        for (int u = tid; u < 8192; u += 512)
          wnl[(u >> 3) * 10 + (u & 7)] = sn[u];
      }
    }
    __syncthreads();  // stage tables ready

    // ---- en (f32, exact-class)
    float sq[8];
#pragma unroll
    for (int k = 0; k < 8; ++k) sq[k] = z[k] * z[k];
    float n2f = s8_exact(sq);
    float nrm = (float)sqrt((double)n2f);
    float den = fmaxf(nrm, 1e-12f);
    float en[8];
#pragma unroll
    for (int k = 0; k < 8; ++k) en[k] = z[k] / den;

    // ---- single-pass f32 scan, 64 interleaved codes/lane, top-4 cache
    float s0 = NEGINF, s1 = NEGINF, s2 = NEGINF, s3 = NEGINF;
    int i0 = 0, i1 = 0, i2 = 0, i3 = 0;
    for (int c = 0; c < 64; ++c) {
      int code = c * 16 + l;
      const float2* cp = (const float2*)&cnl[code * 10];
      float2 a0 = cp[0], a1 = cp[1], a2 = cp[2], a3 = cp[3];
      float s = fmaf(en[0], a0.x, -0.5f * c2l[code]);
      s = fmaf(en[1], a0.y, s);
      s = fmaf(en[2], a1.x, s);
      s = fmaf(en[3], a1.y, s);
      s = fmaf(en[4], a2.x, s);
      s = fmaf(en[5], a2.y, s);
      s = fmaf(en[6], a3.x, s);
      s = fmaf(en[7], a3.y, s);
      if (s > s3) {
        if (s > s2) {
          s3 = s2; i3 = i2;
          if (s > s1) {
            s2 = s1; i2 = i1;
            if (s > s0) {
              s1 = s0; i1 = i0; s0 = s; i0 = code;
            } else { s1 = s; i1 = code; }
          } else { s2 = s; i2 = code; }
        } else { s3 = s; i3 = code; }
      }
    }
    // global f32 max -> prefilter cut
    float g32 = s0;
#pragma unroll
    for (int m = 1; m < 16; m <<= 1) g32 = fmaxf(g32, __shfl_xor(g32, m, 64));
    float cut32 = g32 - PREF32;
    // f64 rescore of qualifying cached codes
    double cs[4];
    int cidx[4] = {i0, i1, i2, i3};
    float sf[4] = {s0, s1, s2, s3};
    double b64 = -1e300;
#pragma unroll
    for (int u = 0; u < 4; ++u) {
      cs[u] = -1e300;
      if (sf[u] >= cut32) {
        const float2* cp = (const float2*)&cnl[cidx[u] * 10];
        float2 a0 = cp[0], a1 = cp[1], a2 = cp[2], a3 = cp[3];
        float cv[8] = {a0.x, a0.y, a1.x, a1.y, a2.x, a2.y, a3.x, a3.y};
        double a = 0.0, q = 0.0;
#pragma unroll
        for (int k = 0; k < 8; ++k) {
          double cd = (double)cv[k];
          a = fma((double)en[k], cd, a);
          q = fma(cd, cd, q);
        }
        cs[u] = a - 0.5 * q;
        if (cs[u] > b64) b64 = cs[u];
      }
    }
#pragma unroll
    for (int m = 1; m < 16; m <<= 1) b64 = fmax(b64, __shfl_xor(b64, m, 64));
    double cut64 = b64 - TOLS;
    int loc = INT_MAX;
#pragma unroll
    for (int u = 0; u < 4; ++u)
      if (cs[u] >= cut64 && cidx[u] < loc) loc = cidx[u];
#pragma unroll
    for (int m = 1; m < 16; m <<= 1) loc = min(loc, __shfl_xor(loc, m, 64));

    // ---- zq_st + outputs + loss
    const float* zp = &cbk[((size_t)i * 1024 + loc) * 8];
    float st[8];
#pragma unroll
    for (int k = 0; k < 8; ++k) {
      float zq = zp[k];
      float dlt = zq - z[k];  // sub eqn f32
      st[k] = z[k] + dlt;     // add eqn f32 (straight-through)
    }
    if (l == 0) {
#pragma unroll
      for (int k = 0; k < 8; ++k) {
        float df = z[k] - zp[k];
        lsum += (double)df * (double)df;
      }
      out[idx_base + ((size_t)b * nq + i) * 2048 + t] = (float)loc;
#pragma unroll
      for (int o = 0; o < 8; ++o)
        out[lat_base + ((size_t)b * (nq * 8) + (i * 8 + o)) * 2048 + t] = z[o];
    }

    // ---- update: resid -= f32(f64 dot8(w_out[d], st)) + bias  (in-register)
#pragma unroll
    for (int j = 0; j < 64; ++j) {
      int d = l + 16 * j;
      const float2* wp = (const float2*)&wol[d * 10];
      float2 wa = wp[0], wb = wp[1], wc = wp[2], wd = wp[3];
      double a = fma((double)wa.x, (double)st[0], 0.0);
      a = fma((double)wa.y, (double)st[1], a);
      a = fma((double)wb.x, (double)st[2], a);
      a = fma((double)wb.y, (double)st[3], a);
      a = fma((double)wc.x, (double)st[4], a);
      a = fma((double)wc.y, (double)st[5], a);
      a = fma((double)wd.x, (double)st[6], a);
      a = fma((double)wd.y, (double)st[7], a);
      float q = (float)a + bol[d];  // add eqn f32
      rr[j] = rr[j] - q;            // sub eqn f32
    }
  }

  // ---- quant = h - resid_final (coalesced via LDS transpose)
#pragma unroll
  for (int cc = 0; cc < 16; ++cc) {
    __syncthreads();
#pragma unroll
    for (int jj = 0; jj < 4; ++jj) hst[l + 16 * jj][g] = rr[cc * 4 + jj];
    __syncthreads();
    int row = tid >> 3, c4 = (tid & 7) * 4;
    size_t adr = ((size_t)b * 1024 + cc * 64 + row) * 2048 + t0 + c4;
    float4 hv = *(const float4*)&h[adr];
    float4 rv = *(float4*)&hst[row][c4];
    float4 qv = {hv.x - rv.x, hv.y - rv.y, hv.z - rv.z, hv.w - rv.w};
    *(float4*)&out[adr] = qv;
  }

  // ---- loss reduce (one atomic per block)
  if (l == 0) lred[g] = lsum;
  __syncthreads();
  if (tid == 0) {
    double s = 0.0;
    for (int u = 0; u < 32; ++u) s += lred[u];
    atomicAdd(loss_acc, s);
  }
}

// --------------------------------------------------------- K3: losses
__global__ void k_fin(const double* __restrict__ loss_acc, int nq,
                      float* __restrict__ out) {
  if (threadIdx.x == 0 && blockIdx.x == 0) {
    float v = (float)(loss_acc[0] / 262144.0);  // B*CD*T
    size_t base = QBASE + (size_t)16 * nq * 2048 + (size_t)16 * nq * 8 * 2048;
    out[base] = v;
    out[base + 1] = v;
  }
}

// ------------------------------------------------------------------ launch
extern "C" void kernel_launch(void* const* d_in, const int* in_sizes, int n_in,
                              void* d_out, int out_size, void* d_ws,
                              size_t ws_size, hipStream_t stream) {
  (void)in_sizes; (void)n_in; (void)ws_size;
  const float* h     = (const float*)d_in[0];
  const float* in_v  = (const float*)d_in[1];
  const float* in_g  = (const float*)d_in[2];
  const float* in_b  = (const float*)d_in[3];
  const float* out_v = (const float*)d_in[4];
  const float* out_g = (const float*)d_in[5];
  const float* out_b = (const float*)d_in[6];
  const float* cbk   = (const float*)d_in[7];
  float* out = (float*)d_out;
  char* ws = (char*)d_ws;

  long long nq_ll = ((long long)out_size - (long long)QBASE - 2) / 294912LL;
  int nq = (int)nq_ll;
  if (nq < 1) nq = 1;
  if (nq > 9) nq = 9;

  size_t off = 0;
  auto alloc = [&](size_t bytes) {
    size_t o = off;
    off += (bytes + 255) & ~(size_t)255;
    return o;
  };
  float*  w_inT  = (float*)(ws + alloc((size_t)9 * 1024 * 8 * 4));
  float*  w_outT = (float*)(ws + alloc((size_t)9 * 1024 * 8 * 4));
  float*  cnf    = (float*)(ws + alloc((size_t)9 * 1024 * 8 * 4));
  float*  cn2    = (float*)(ws + alloc((size_t)9 * 1024 * 4));
  double* lossa  = (double*)(ws + alloc(256));

  k_prep<<<dim3(144), 256, 0, stream>>>(in_v, in_g, out_v, out_g, cbk, w_inT,
                                        w_outT, cnf, cn2, lossa);
  k_fused<<<dim3(1024), 512, 0, stream>>>(h, w_inT, w_outT, in_b, out_b, cnf,
                                          cn2, cbk, nq, out, lossa);
  k_fin<<<1, 64, 0, stream>>>(lossa, nq, out);
}

// Round 11
// 736.068 us; speedup vs baseline: 2.3849x; 1.5896x over previous
//
#include <hip/hip_runtime.h>
#include <cstdint>
#include <cstddef>
#include <climits>

// DacResidualVectorQuantize on MI355X. Exact-class (f64-internal, f32
// materialization) chain + cluster-argmin — green since R7 (indices exact).
// R11: occupancy 1->2 blocks/CU. LDS 140.5KB -> ~68KB via (a) pair-rotation
// swizzle (no padding, conflict-free b64), (b) A/B phase-alternated tables,
// (c) hst aliasing the table arena, (d) shared c2/bias buffer. Scan: top-2
// per-lane cache (was top-4); prestored 0.5*cn2.

#define NCOL 32768
#define QBASE 33554432ull  // 16*1024*2048
#define PREF32 2e-5f       // f32 prefilter band (score units)
#define TOLS 1.25e-7       // score tolerance (= dist tol 2.5e-7 / 2)
#define NEGINF (-__builtin_inff())

// f32 round of exact sum of 8 f32 values
__device__ __forceinline__ float s8_exact(const float* x) {
  double a = 0.0;
#pragma unroll
  for (int k = 0; k < 8; ++k) a += (double)x[k];
  return (float)a;
}

// -------------------------------------------------------------- K1: prep
// blocks [0,72): one block per w_in row (parallel norm reduce).
// blocks [72,144): flat threads for w_out rows (9216) + codebook rows (9216).
__global__ __launch_bounds__(256) void k_prep(
    const float* __restrict__ in_v, const float* __restrict__ in_g,
    const float* __restrict__ out_v, const float* __restrict__ out_g,
    const float* __restrict__ cbk, float* __restrict__ w_inT,
    float* __restrict__ w_outT, float* __restrict__ cnf,
    float* __restrict__ cn2h, double* __restrict__ loss_acc) {
#pragma clang fp contract(off)
  __shared__ double red[256];
  int bid = blockIdx.x, tid = threadIdx.x;
  if (bid == 0 && tid == 0) loss_acc[0] = 0.0;
  if (bid < 72) {
    int i = bid >> 3, o = bid & 7;
    const float* v = in_v + (size_t)bid * 1024;
    double p = 0.0;
    for (int d = tid; d < 1024; d += 256) {
      float sqv = v[d] * v[d];  // integer_pow eqn f32
      p += (double)sqv;         // exact accumulation
    }
    red[tid] = p;
    __syncthreads();
    for (int s = 128; s > 0; s >>= 1) {
      if (tid < s) red[tid] += red[tid + s];
      __syncthreads();
    }
    float n2f = (float)red[0];             // reduce_sum -> f32 aval
    float nrm = (float)sqrt((double)n2f);  // correctly-rounded f32 sqrt
    float g = in_g[bid];
    for (int d = tid; d < 1024; d += 256) {
      float gv = g * v[d];  // mul eqn f32
      float w = gv / nrm;   // div eqn f32
      w_inT[((size_t)i * 1024 + d) * 8 + o] = w;
    }
  } else {
    int id = (bid - 72) * 256 + tid;
    if (id < 9216) {
      int r = id;  // (i,d) row of out_v [9][1024][8]
      const float* v = out_v + (size_t)r * 8;
      float sq[8];
#pragma unroll
      for (int k = 0; k < 8; ++k) sq[k] = v[k] * v[k];
      float n2f = s8_exact(sq);
      float nrm = (float)sqrt((double)n2f);
      float g = out_g[r];
#pragma unroll
      for (int k = 0; k < 8; ++k) {
        float gv = g * v[k];
        w_outT[(size_t)r * 8 + k] = gv / nrm;
      }
    } else if (id < 18432) {
      int r = id - 9216;  // code row (i*1024+c)
      const float* v = cbk + (size_t)r * 8;
      float sq[8];
#pragma unroll
      for (int k = 0; k < 8; ++k) sq[k] = v[k] * v[k];
      float n2f = s8_exact(sq);
      float nrm = (float)sqrt((double)n2f);
      float den = fmaxf(nrm, 1e-12f);
      float cn[8], c2[8];
#pragma unroll
      for (int k = 0; k < 8; ++k) {
        cn[k] = v[k] / den;
        cnf[(size_t)r * 8 + k] = cn[k];
        c2[k] = cn[k] * cn[k];
      }
      cn2h[r] = 0.5f * s8_exact(c2);  // exact halving, used by f32 prefilter
    }
  }
}

// ------------------------------------------------ K2: fused 9-stage VQ
// 512 thr = 32 columns x 16 lanes; rr[64] f32 regs = resid slice (d=l+16j).
// LDS: tabs[16384] = two 8192-float swizzled tables (A/B roles alternate;
// also aliased as 64x36 hst tile at init/final), smal[1024] (c2 or bias).
// Swizzle: row r stores float2-pair p at slot (p + (r>>2)) & 3. For all hot
// patterns (d = l+16j, code = 16c+l) rot = (l>>2)&3 is lane-constant and the
// 16 lanes hit 16 distinct banks (4-way broadcast across column groups).
__global__ __launch_bounds__(512, 4) void k_fused(
    const float* __restrict__ h, const float* __restrict__ w_inT,
    const float* __restrict__ w_outT, const float* __restrict__ in_b,
    const float* __restrict__ out_b, const float* __restrict__ cnf,
    const float* __restrict__ cn2h, const float* __restrict__ cbk, int nq,
    float* __restrict__ out, double* __restrict__ loss_acc) {
#pragma clang fp contract(off)
  __shared__ float tabs[16384];
  __shared__ float smal[1024];
  __shared__ double lred[32];

  int tid = threadIdx.x;
  int g = tid >> 4;  // column group 0..31
  int l = tid & 15;  // lane in group
  int b = blockIdx.x >> 6;
  int t0 = (blockIdx.x & 63) * 32;
  int t = t0 + g;
  int rot = (l >> 2) & 3;
  int a0 = ((0 + rot) & 3) * 2;
  int a1 = ((1 + rot) & 3) * 2;
  int a2 = ((2 + rot) & 3) * 2;
  int a3 = ((3 + rot) & 3) * 2;

  // swizzled staging: 8-float rows, pair p -> slot (p + (r>>2))&3
  auto stage_tab = [&](float* dst, const float* src) {
    for (int u2 = tid; u2 < 4096; u2 += 512) {
      int r = u2 >> 2, p = u2 & 3;
      float2 v = *(const float2*)&src[(size_t)r * 8 + p * 2];
      int pp = (p + ((r >> 2) & 3)) & 3;
      *(float2*)&dst[r * 8 + pp * 2] = v;
    }
  };

  // ---- load resid = h into registers (coalesced via hst tile = tabs alias)
  float rr[64];
  {
    float* hst = tabs;  // [64][36]
#pragma unroll
    for (int cc = 0; cc < 16; ++cc) {
      __syncthreads();
      int row = tid >> 3, c4 = (tid & 7) * 4;
      *(float4*)&hst[row * 36 + c4] =
          *(const float4*)&h[((size_t)b * 1024 + cc * 64 + row) * 2048 + t0 + c4];
      __syncthreads();
#pragma unroll
      for (int jj = 0; jj < 4; ++jj)
        rr[cc * 4 + jj] = hst[(l + 16 * jj) * 36 + g];
    }
  }
  __syncthreads();

  float* fb = tabs;         // fold buffer (w_in[i])
  float* ob = tabs + 8192;  // other buffer (cn[i] / next w_in)
  stage_tab(fb, w_inT);     // w_in[0]
  __syncthreads();

  double lsum = 0.0;
  size_t idx_base = QBASE;
  size_t lat_base = QBASE + (size_t)16 * nq * 2048;

  for (int i = 0; i < nq; ++i) {
    // ---- fold: z_e = w_in[i] . resid (f64 exact-class)
    double za[8] = {0, 0, 0, 0, 0, 0, 0, 0};
    {
      const float* rp = fb + l * 8;
#pragma unroll
      for (int j = 0; j < 64; ++j) {
        float2 wa = *(const float2*)&rp[a0];
        float2 wb = *(const float2*)&rp[a1];
        float2 wc = *(const float2*)&rp[a2];
        float2 wd = *(const float2*)&rp[a3];
        double rv = (double)rr[j];
        za[0] = fma((double)wa.x, rv, za[0]);
        za[1] = fma((double)wa.y, rv, za[1]);
        za[2] = fma((double)wb.x, rv, za[2]);
        za[3] = fma((double)wb.y, rv, za[3]);
        za[4] = fma((double)wc.x, rv, za[4]);
        za[5] = fma((double)wc.y, rv, za[5]);
        za[6] = fma((double)wd.x, rv, za[6]);
        za[7] = fma((double)wd.y, rv, za[7]);
        rp += 128;
      }
    }
#pragma unroll
    for (int o = 0; o < 8; ++o) {
#pragma unroll
      for (int m = 1; m < 16; m <<= 1) za[o] += __shfl_xor(za[o], m, 64);
    }
    float z[8];
#pragma unroll
    for (int o = 0; o < 8; ++o)
      z[o] = (float)za[o] + in_b[i * 8 + o];  // add eqn f32
    __syncthreads();  // fb free (fold done)

    // ---- load cn[i] into ob, 0.5*cn2 into smal
    stage_tab(ob, cnf + (size_t)i * 8192);
    for (int u = tid; u < 1024; u += 512) smal[u] = cn2h[i * 1024 + u];
    __syncthreads();

    // ---- en (f32, exact-class)
    float sq[8];
#pragma unroll
    for (int k = 0; k < 8; ++k) sq[k] = z[k] * z[k];
    float n2f = s8_exact(sq);
    float nrm = (float)sqrt((double)n2f);
    float den = fmaxf(nrm, 1e-12f);
    float en[8];
#pragma unroll
    for (int k = 0; k < 8; ++k) en[k] = z[k] / den;

    // ---- f32 scan, 64 interleaved codes/lane, top-2 cache
    float s0 = NEGINF, s1 = NEGINF;
    int i0 = 0, i1 = 0;
    {
      const float* rp = ob + l * 8;
      int code = l;
      for (int c = 0; c < 64; ++c) {
        float2 A0 = *(const float2*)&rp[a0];
        float2 A1 = *(const float2*)&rp[a1];
        float2 A2 = *(const float2*)&rp[a2];
        float2 A3 = *(const float2*)&rp[a3];
        float s = fmaf(en[0], A0.x, -smal[code]);
        s = fmaf(en[1], A0.y, s);
        s = fmaf(en[2], A1.x, s);
        s = fmaf(en[3], A1.y, s);
        s = fmaf(en[4], A2.x, s);
        s = fmaf(en[5], A2.y, s);
        s = fmaf(en[6], A3.x, s);
        s = fmaf(en[7], A3.y, s);
        if (s > s1) {
          if (s > s0) {
            s1 = s0; i1 = i0; s0 = s; i0 = code;
          } else {
            s1 = s; i1 = code;
          }
        }
        rp += 128;
        code += 16;
      }
    }
    // global f32 max -> prefilter cut
    float g32 = s0;
#pragma unroll
    for (int m = 1; m < 16; m <<= 1) g32 = fmaxf(g32, __shfl_xor(g32, m, 64));
    float cut32 = g32 - PREF32;
    // f64 rescore of qualifying cached codes
    double cs[2];
    int cidx[2] = {i0, i1};
    float sf[2] = {s0, s1};
    double b64 = -1e300;
#pragma unroll
    for (int u = 0; u < 2; ++u) {
      cs[u] = -1e300;
      if (sf[u] >= cut32) {
        int r = cidx[u];
        int ru = (r >> 2) & 3;
        const float* rp = ob + r * 8;
        float2 A0 = *(const float2*)&rp[((0 + ru) & 3) * 2];
        float2 A1 = *(const float2*)&rp[((1 + ru) & 3) * 2];
        float2 A2 = *(const float2*)&rp[((2 + ru) & 3) * 2];
        float2 A3 = *(const float2*)&rp[((3 + ru) & 3) * 2];
        float cv[8] = {A0.x, A0.y, A1.x, A1.y, A2.x, A2.y, A3.x, A3.y};
        double a = 0.0, q = 0.0;
#pragma unroll
        for (int k = 0; k < 8; ++k) {
          double cd = (double)cv[k];
          a = fma((double)en[k], cd, a);
          q = fma(cd, cd, q);
        }
        cs[u] = a - 0.5 * q;
        if (cs[u] > b64) b64 = cs[u];
      }
    }
#pragma unroll
    for (int m = 1; m < 16; m <<= 1) b64 = fmax(b64, __shfl_xor(b64, m, 64));
    double cut64 = b64 - TOLS;
    int loc = INT_MAX;
#pragma unroll
    for (int u = 0; u < 2; ++u)
      if (cs[u] >= cut64 && cidx[u] < loc) loc = cidx[u];
#pragma unroll
    for (int m = 1; m < 16; m <<= 1) loc = min(loc, __shfl_xor(loc, m, 64));
    __syncthreads();  // ob free (scan done)

    // ---- load w_out[i] -> fb, bias -> smal, w_in[i+1] -> ob
    stage_tab(fb, w_outT + (size_t)i * 8192);
    for (int u = tid; u < 1024; u += 512) smal[u] = out_b[i * 1024 + u];
    if (i + 1 < nq) stage_tab(ob, w_inT + (size_t)(i + 1) * 8192);
    __syncthreads();

    // ---- zq_st + outputs + loss
    const float* zp = &cbk[((size_t)i * 1024 + loc) * 8];
    float st[8];
#pragma unroll
    for (int k = 0; k < 8; ++k) {
      float zq = zp[k];
      float dlt = zq - z[k];  // sub eqn f32
      st[k] = z[k] + dlt;     // add eqn f32 (straight-through)
    }
    if (l == 0) {
#pragma unroll
      for (int k = 0; k < 8; ++k) {
        float df = z[k] - zp[k];
        lsum += (double)df * (double)df;
      }
      out[idx_base + ((size_t)b * nq + i) * 2048 + t] = (float)loc;
#pragma unroll
      for (int o = 0; o < 8; ++o)
        out[lat_base + ((size_t)b * (nq * 8) + (i * 8 + o)) * 2048 + t] = z[o];
    }

    // ---- update: resid -= f32(f64 dot8(w_out[d], st)) + bias (in-register)
    {
      const float* rp = fb + l * 8;
      int d = l;
#pragma unroll
      for (int j = 0; j < 64; ++j) {
        float2 wa = *(const float2*)&rp[a0];
        float2 wb = *(const float2*)&rp[a1];
        float2 wc = *(const float2*)&rp[a2];
        float2 wd = *(const float2*)&rp[a3];
        double a = fma((double)wa.x, (double)st[0], 0.0);
        a = fma((double)wa.y, (double)st[1], a);
        a = fma((double)wb.x, (double)st[2], a);
        a = fma((double)wb.y, (double)st[3], a);
        a = fma((double)wc.x, (double)st[4], a);
        a = fma((double)wc.y, (double)st[5], a);
        a = fma((double)wd.x, (double)st[6], a);
        a = fma((double)wd.y, (double)st[7], a);
        float q = (float)a + smal[d];  // add eqn f32
        rr[j] = rr[j] - q;             // sub eqn f32
        rp += 128;
        d += 16;
      }
    }
    // swap roles: ob holds w_in[i+1] -> next fold buffer
    float* tmp = fb; fb = ob; ob = tmp;
  }

  // ---- quant = h - resid_final (coalesced via hst tile = tabs alias)
  {
    float* hst = tabs;
#pragma unroll
    for (int cc = 0; cc < 16; ++cc) {
      __syncthreads();
#pragma unroll
      for (int jj = 0; jj < 4; ++jj)
        hst[(l + 16 * jj) * 36 + g] = rr[cc * 4 + jj];
      __syncthreads();
      int row = tid >> 3, c4 = (tid & 7) * 4;
      size_t adr = ((size_t)b * 1024 + cc * 64 + row) * 2048 + t0 + c4;
      float4 hv = *(const float4*)&h[adr];
      float4 rv = *(float4*)&hst[row * 36 + c4];
      float4 qv = {hv.x - rv.x, hv.y - rv.y, hv.z - rv.z, hv.w - rv.w};
      *(float4*)&out[adr] = qv;
    }
  }

  // ---- loss reduce (one atomic per block)
  if (l == 0) lred[g] = lsum;
  __syncthreads();
  if (tid == 0) {
    double s = 0.0;
    for (int u = 0; u < 32; ++u) s += lred[u];
    atomicAdd(loss_acc, s);
  }
}

// --------------------------------------------------------- K3: losses
__global__ void k_fin(const double* __restrict__ loss_acc, int nq,
                      float* __restrict__ out) {
  if (threadIdx.x == 0 && blockIdx.x == 0) {
    float v = (float)(loss_acc[0] / 262144.0);  // B*CD*T
    size_t base = QBASE + (size_t)16 * nq * 2048 + (size_t)16 * nq * 8 * 2048;
    out[base] = v;
    out[base + 1] = v;
  }
}

// ------------------------------------------------------------------ launch
extern "C" void kernel_launch(void* const* d_in, const int* in_sizes, int n_in,
                              void* d_out, int out_size, void* d_ws,
                              size_t ws_size, hipStream_t stream) {
  (void)in_sizes; (void)n_in; (void)ws_size;
  const float* h     = (const float*)d_in[0];
  const float* in_v  = (const float*)d_in[1];
  const float* in_g  = (const float*)d_in[2];
  const float* in_b  = (const float*)d_in[3];
  const float* out_v = (const float*)d_in[4];
  const float* out_g = (const float*)d_in[5];
  const float* out_b = (const float*)d_in[6];
  const float* cbk   = (const float*)d_in[7];
  float* out = (float*)d_out;
  char* ws = (char*)d_ws;

  long long nq_ll = ((long long)out_size - (long long)QBASE - 2) / 294912LL;
  int nq = (int)nq_ll;
  if (nq < 1) nq = 1;
  if (nq > 9) nq = 9;

  size_t off = 0;
  auto alloc = [&](size_t bytes) {
    size_t o = off;
    off += (bytes + 255) & ~(size_t)255;
    return o;
  };
  float*  w_inT  = (float*)(ws + alloc((size_t)9 * 1024 * 8 * 4));
  float*  w_outT = (float*)(ws + alloc((size_t)9 * 1024 * 8 * 4));
  float*  cnf    = (float*)(ws + alloc((size_t)9 * 1024 * 8 * 4));
  float*  cn2h   = (float*)(ws + alloc((size_t)9 * 1024 * 4));
  double* lossa  = (double*)(ws + alloc(256));

  k_prep<<<dim3(144), 256, 0, stream>>>(in_v, in_g, out_v, out_g, cbk, w_inT,
                                        w_outT, cnf, cn2h, lossa);
  k_fused<<<dim3(1024), 512, 0, stream>>>(h, w_inT, w_outT, in_b, out_b, cnf,
                                          cn2h, cbk, nq, out, lossa);
  k_fin<<<1, 64, 0, stream>>>(lossa, nq, out);
}